// Round 7
// baseline (588.283 us; speedup 1.0000x reference)
//
#include <hip/hip_runtime.h>
#include <math.h>

// MultiHeadDotAttn: B=64, S=2048, QD=1024, KD=512, AD=512, H=8
//
// Algebraic reordering: qk[b,h,d] = sum_a q[b,h,a]*Wk[h,a,d], then
// energy[b,h,s] = dot(keys[b,s,:], qk[b,h,:]). Masked positions (s>=key_len)
// are exact zeros after softmax (f32 underflow), so keys/value reads there
// are skipped entirely.
//
// R4 (resubmitted; infra timeouts):
//  - K2 stores qk TRANSPOSED: qkT[b][d][h] (head-minor) so 8 heads at dim d
//    are contiguous -> wave-uniform scalar loads in K3.
//  - K3 lane-per-row: lane computes full 512-dim dot for one s-row for all
//    8 heads. qk via uniform (s_load) reads, keys streamed per-lane through
//    L1 (8KB live lines/wave). NO shuffles / NO LDS / no main-loop divergence.
//  - K5 chunk 128 rows: part traffic 24MB round trip, no atomics.

#define B_  64
#define S_  2048
#define QD_ 1024
#define KD_ 512
#define AD_ 512
#define H_  8

// ---------------------------------------------------------------------------
// K1: q[b, n] = sum_k query[b,k] * Wq[n,k],  n = h*AD+a  (C = A @ W^T, NT)
// grid (4 m-tiles of 16, 64 n-tiles of 64), block 256
__global__ __launch_bounds__(256) void k1_qproj(const float* __restrict__ query,
                                                const float* __restrict__ Wq,
                                                float* __restrict__ qo) {
    __shared__ float As[16][65];
    __shared__ float Ws[64][65];
    const int t = threadIdx.x;
    const int m0 = blockIdx.x * 16, n0 = blockIdx.y * 64;
    const int nl = t & 63, mb = (t >> 6) * 4;
    float acc[4] = {0.f, 0.f, 0.f, 0.f};
    for (int kc = 0; kc < QD_; kc += 64) {
#pragma unroll
        for (int i = 0; i < 4; ++i) {
            int idx = t + i * 256, r = idx >> 6, c = idx & 63;
            As[r][c] = query[(m0 + r) * QD_ + kc + c];
        }
#pragma unroll
        for (int i = 0; i < 16; ++i) {
            int idx = t + i * 256, r = idx >> 6, c = idx & 63;
            Ws[r][c] = Wq[(size_t)(n0 + r) * QD_ + kc + c];
        }
        __syncthreads();
#pragma unroll
        for (int k = 0; k < 64; ++k) {
            float w = Ws[nl][k];
#pragma unroll
            for (int j = 0; j < 4; ++j) acc[j] += As[mb + j][k] * w;
        }
        __syncthreads();
    }
#pragma unroll
    for (int j = 0; j < 4; ++j)
        qo[(m0 + mb + j) * (H_ * AD_) + n0 + nl] = acc[j];
}

// ---------------------------------------------------------------------------
// K2: qkT[b, d, h] = sum_a q[b, h*AD+a] * Wk[h,a,d]   (per-head TN GEMM,
// transposed head-minor store for K3's uniform loads)
// grid (4 m-tiles, 8 n-tiles, 8 heads), block 256
__global__ __launch_bounds__(256) void k2_qk(const float* __restrict__ q,
                                             const float* __restrict__ Wk,
                                             float* __restrict__ qkT) {
    __shared__ float As[16][65];
    __shared__ float Ws[64][65];  // [k][n]
    const int t = threadIdx.x;
    const int m0 = blockIdx.x * 16, n0 = blockIdx.y * 64, h = blockIdx.z;
    const float* Wh = Wk + (size_t)h * AD_ * KD_;
    const int nl = t & 63, mb = (t >> 6) * 4;
    float acc[4] = {0.f, 0.f, 0.f, 0.f};
    for (int ac = 0; ac < AD_; ac += 64) {
#pragma unroll
        for (int i = 0; i < 4; ++i) {
            int idx = t + i * 256, r = idx >> 6, c = idx & 63;
            As[r][c] = q[(m0 + r) * (H_ * AD_) + h * AD_ + ac + c];
        }
#pragma unroll
        for (int i = 0; i < 16; ++i) {
            int idx = t + i * 256, r = idx >> 6, c = idx & 63;  // r = k, c = n
            Ws[r][c] = Wh[(size_t)(ac + r) * KD_ + n0 + c];
        }
        __syncthreads();
#pragma unroll
        for (int k = 0; k < 64; ++k) {
            float w = Ws[k][nl];
#pragma unroll
            for (int j = 0; j < 4; ++j) acc[j] += As[mb + j][k] * w;
        }
        __syncthreads();
    }
    // qkT[b][d][h], b = m0+mb+j, d = n0+nl
#pragma unroll
    for (int j = 0; j < 4; ++j)
        qkT[((size_t)(m0 + mb + j) * KD_ + (n0 + nl)) * H_ + h] = acc[j];
}

// ---------------------------------------------------------------------------
// K3: energy[b,h,s] = dot(keys[b,s,:KD], qkT[b,:,h])
// Lane-per-row: lane owns one s-row, computes all 8 heads. qkT reads are
// wave-uniform (scalar loads); keys stream per-lane through L1.
// grid (16 s-chunks of 128, 64 b), block 128 (2 waves)
__global__ __launch_bounds__(128) void k3_energy(const float* __restrict__ keys,
                                                 const float* __restrict__ qkT,
                                                 const int* __restrict__ key_len,
                                                 float* __restrict__ energy) {
    const int b = blockIdx.y;
    const int klen = key_len[b];
    const int s_base = blockIdx.x * 128;
    if (s_base >= klen) return;  // fully masked: energy never read downstream
    const int t = threadIdx.x;
    const int row = s_base + t;  // < S_ always (16*128 == S_)

    const float* __restrict__ qb = qkT + (size_t)b * (KD_ * H_);  // wave-uniform
    const float4* __restrict__ kr =
        reinterpret_cast<const float4*>(keys + (size_t)(b * S_ + row) * KD_);

    float acc[8];
#pragma unroll
    for (int h = 0; h < H_; ++h) acc[h] = 0.f;

#pragma unroll 2
    for (int j4 = 0; j4 < KD_ / 4; ++j4) {
        const float4 kv = kr[j4];
        const float* qd = qb + (size_t)j4 * 4 * H_;  // uniform
#pragma unroll
        for (int h = 0; h < H_; ++h) acc[h] += kv.x * qd[h];
#pragma unroll
        for (int h = 0; h < H_; ++h) acc[h] += kv.y * qd[H_ + h];
#pragma unroll
        for (int h = 0; h < H_; ++h) acc[h] += kv.z * qd[2 * H_ + h];
#pragma unroll
        for (int h = 0; h < H_; ++h) acc[h] += kv.w * qd[3 * H_ + h];
    }

    if (row < klen) {
#pragma unroll
        for (int h = 0; h < H_; ++h)
            energy[((size_t)b * H_ + h) * S_ + row] = acc[h];
    }
}

// ---------------------------------------------------------------------------
// K4: masked softmax over S per (b,h) row; writes attn output.
// grid 512 (= B*H), block 256.
__global__ __launch_bounds__(256) void k4_softmax(const float* __restrict__ energy,
                                                  const int* __restrict__ key_len,
                                                  float* __restrict__ attn) {
    const int bh = blockIdx.x;  // b*H + h
    const int b = bh >> 3;
    const int t = threadIdx.x;

    const int klen = key_len[b];
    const float* e = energy + (size_t)bh * S_;
    float ev[8];
    float m = -3.0e38f;
#pragma unroll
    for (int j = 0; j < 8; ++j) {
        int s = t + j * 256;
        float x = (s < klen) ? e[s] : -3.0e38f;
        ev[j] = x;
        m = fmaxf(m, x);
    }
#pragma unroll
    for (int off = 32; off >= 1; off >>= 1) m = fmaxf(m, __shfl_xor(m, off, 64));
    __shared__ float redm[4];
    if ((t & 63) == 0) redm[t >> 6] = m;
    __syncthreads();
    m = fmaxf(fmaxf(redm[0], redm[1]), fmaxf(redm[2], redm[3]));

    float sum = 0.f;
#pragma unroll
    for (int j = 0; j < 8; ++j) {
        int s = t + j * 256;
        float p = (s < klen) ? __expf(ev[j] - m) : 0.f;
        ev[j] = p;
        sum += p;
    }
#pragma unroll
    for (int off = 32; off >= 1; off >>= 1) sum += __shfl_xor(sum, off, 64);
    __shared__ float reds[4];
    if ((t & 63) == 0) reds[t >> 6] = sum;
    __syncthreads();
    sum = reds[0] + reds[1] + reds[2] + reds[3];
    const float inv = 1.f / sum;

    float* a = attn + (size_t)bh * S_;
#pragma unroll
    for (int j = 0; j < 8; ++j) a[t + j * 256] = ev[j] * inv;  // masked -> exact 0
}

// ---------------------------------------------------------------------------
// K5: partial context per 128-row chunk p: part[p][b][h][d] = sum_{s in chunk}
// attn[b,h,s]*value[b,s,d]. grid (8 s-chunks of 256, 64 b), block 256 =
// 128 float4-cols x 2 s-halves of 128 rows. No atomics.
__global__ __launch_bounds__(256) void k5_context(const float* __restrict__ value,
                                                  const float* __restrict__ attn,
                                                  const int* __restrict__ key_len,
                                                  float* __restrict__ part) {
    const int b = blockIdx.y;
    const int klen = key_len[b];
    const int s_base = blockIdx.x * 256;
    if (s_base >= klen) return;  // attn is exactly 0 there
    const int t = threadIdx.x;

    __shared__ float at[8][256];
#pragma unroll
    for (int i = 0; i < 8; ++i) {
        int idx = t + i * 256, h = idx >> 8, si = idx & 255;
        int s = s_base + si;
        at[h][si] = (s < klen) ? attn[((size_t)b * H_ + h) * S_ + s] : 0.f;
    }
    __syncthreads();

    const int col = t & 127;   // float4 column index
    const int sh = t >> 7;     // s-half 0/1 (128 rows each)
    const int d = col * 4;
    const int base_si = sh * 128;
    const int valid = min(128, klen - s_base - base_si);
    if (valid <= 0) return;  // this partial chunk is excluded by K6

    float4 acc[8];
#pragma unroll
    for (int h = 0; h < H_; ++h) acc[h] = make_float4(0.f, 0.f, 0.f, 0.f);

    auto step = [&](int si) {
        const float4 v = *reinterpret_cast<const float4*>(
            value + (size_t)(b * S_ + s_base + base_si + si) * KD_ + d);
#pragma unroll
        for (int h = 0; h < H_; ++h) {
            const float a = at[h][base_si + si];
            acc[h].x += a * v.x; acc[h].y += a * v.y;
            acc[h].z += a * v.z; acc[h].w += a * v.w;
        }
    };
    if (valid == 128) {
#pragma unroll 4
        for (int si = 0; si < 128; ++si) step(si);
    } else {
        for (int si = 0; si < valid; ++si) step(si);
    }

    const int p = blockIdx.x * 2 + sh;  // 128-row chunk index, 0..15
    float* pp = part + (((size_t)p * B_ + b) * H_) * KD_;
#pragma unroll
    for (int h = 0; h < H_; ++h)
        *reinterpret_cast<float4*>(pp + h * KD_ + d) = acc[h];
}

// ---------------------------------------------------------------------------
// K6: ctx[b,h,d] = sum_{p < ceil(klen/128)} part[p][b][h][d]
// grid 256, block 256: one float4 per thread (65536 total).
__global__ __launch_bounds__(256) void k6_reduce(const float* __restrict__ part,
                                                 const int* __restrict__ key_len,
                                                 float* __restrict__ ctx) {
    const int g = blockIdx.x * 256 + threadIdx.x;  // float4 index
    const int d4 = g & 127;
    const int h = (g >> 7) & 7;
    const int b = g >> 10;
    const int nc = (key_len[b] + 127) >> 7;  // live chunks; only these were written
    float4 s = make_float4(0.f, 0.f, 0.f, 0.f);
    for (int p = 0; p < nc; ++p) {
        const float4 v = *reinterpret_cast<const float4*>(
            part + (((size_t)p * B_ + b) * H_ + h) * KD_ + d4 * 4);
        s.x += v.x; s.y += v.y; s.z += v.z; s.w += v.w;
    }
    *reinterpret_cast<float4*>(ctx + ((size_t)b * H_ + h) * KD_ + d4 * 4) = s;
}

// ---------------------------------------------------------------------------
extern "C" void kernel_launch(void* const* d_in, const int* in_sizes, int n_in,
                              void* d_out, int out_size, void* d_ws, size_t ws_size,
                              hipStream_t stream) {
    const float* query   = (const float*)d_in[0];  // (B, QD)
    const float* keys    = (const float*)d_in[1];  // (B, S, KD)
    const float* value   = (const float*)d_in[2];  // (B, S, KD)
    const int*   key_len = (const int*)d_in[3];    // (B,)
    const float* Wq      = (const float*)d_in[4];  // (H, AD, QD)
    const float* Wk      = (const float*)d_in[5];  // (H, AD, KD)

    float* out = (float*)d_out;
    float* ctx_out  = out;                          // (B, H*KD) = 262144 floats
    float* attn_out = out + (size_t)B_ * H_ * KD_;  // (B, H, S) = 1048576 floats

    float* ws      = (float*)d_ws;
    float* q_ws    = ws;                                   // B*H*AD = 262144
    float* qkT_ws  = ws + (size_t)B_ * H_ * AD_;           // B*KD*H = 262144
    float* e_ws    = qkT_ws + (size_t)B_ * KD_ * H_;       // B*H*S  = 1048576
    float* part_ws = e_ws + (size_t)B_ * H_ * S_;          // 16*B*H*KD = 4194304

    hipLaunchKernelGGL(k1_qproj, dim3(4, 64), dim3(256), 0, stream, query, Wq, q_ws);
    hipLaunchKernelGGL(k2_qk, dim3(4, 8, 8), dim3(256), 0, stream, q_ws, Wk, qkT_ws);
    hipLaunchKernelGGL(k3_energy, dim3(16, 64), dim3(128), 0, stream,
                       keys, qkT_ws, key_len, e_ws);
    hipLaunchKernelGGL(k4_softmax, dim3(512), dim3(256), 0, stream,
                       e_ws, key_len, attn_out);
    hipLaunchKernelGGL(k5_context, dim3(8, 64), dim3(256), 0, stream,
                       value, attn_out, key_len, part_ws);
    hipLaunchKernelGGL(k6_reduce, dim3(256), dim3(256), 0, stream,
                       part_ws, key_len, ctx_out);
}